// Round 7
// baseline (123.403 us; speedup 1.0000x reference)
//
#include <hip/hip_runtime.h>
#include <hip/hip_bf16.h>

// Problem config
#define B_     4
#define S_     1024
#define H_     16
#define KVH_   4
#define D_     64
#define N_     (B_*S_)        // 4096
#define SLOTS_ 8192
#define KVD_   (KVH_*D_)      // 256
#define HD_    (H_*D_)        // 1024
#define SCL    (0.125f * 1.44269504f)   // softmax scale * log2(e), folded into Q

#define NATT   1024           // attn blocks in fused launch
#define NCACHE 4096           // cache blocks: SLOTS_*64 float4 / 128 thr

typedef __attribute__((ext_vector_type(8))) short bf16x8;
typedef __attribute__((ext_vector_type(4))) short bf16x4;
typedef __attribute__((ext_vector_type(4))) float f32x4;

__device__ __forceinline__ short4 f4tob4(float4 f){
    union { __hip_bfloat162 h[2]; short4 s; } u;
    u.h[0] = __float22bfloat162_rn(make_float2(f.x, f.y));
    u.h[1] = __float22bfloat162_rn(make_float2(f.z, f.w));
    return u.s;
}
// XOR swizzle on a 64-col short tile: 8-element groups stay contiguous,
// strided accesses spread across banks (<=2-way, free per m136).
__device__ __forceinline__ int swz(int row, int col){
    return row*64 + (col ^ ((row & 7) << 3));
}

// ---------------------------------------------------------------------------
// L1: init inverse slot map
// ---------------------------------------------------------------------------
__global__ void inv_init(int* __restrict__ inv){
    inv[blockIdx.x*256 + threadIdx.x] = -1;
}

// ---------------------------------------------------------------------------
// L2 fused: blocks 0..255 = prep (bf16 operand arrays), 256..271 = inv scatter
// ---------------------------------------------------------------------------
__global__ __launch_bounds__(256) void prep_kernel(
    const float* __restrict__ k, const float* __restrict__ v,
    const int* __restrict__ slot_map, int* __restrict__ inv,
    short* __restrict__ Kb, short* __restrict__ Vtb)
{
    const int tid = threadIdx.x;
    if (blockIdx.x >= 256){                    // inverse-map scatter
        int i = (blockIdx.x - 256)*256 + tid;  // over N_
        int s = slot_map[i];
        if (s >= 0 && s < SLOTS_) inv[s] = i;
        return;
    }
    __shared__ short sv[64*68];                // bf16 v-slice, pad 68
    const int g   = blockIdx.x >> 4;           // 0..15 = b*4 + kvh
    const int s0  = (blockIdx.x & 15) * 64;
    const int b   = g >> 2, kvh = g & 3;

    const int sl = tid >> 2;                   // token-local 0..63
    const int cq = (tid & 3) * 16;             // dim chunk 0..48

    const int n   = b*S_ + s0 + sl;
    const float4* kp = (const float4*)(k + (size_t)n*KVD_ + kvh*D_ + cq);
    const float4* vp = (const float4*)(v + (size_t)n*KVD_ + kvh*D_ + cq);

    float4 kk[4], vv[4];
    #pragma unroll
    for (int j = 0; j < 4; ++j){ kk[j] = kp[j]; vv[j] = vp[j]; }

    short* kbp = Kb + ((size_t)g*S_ + s0 + sl)*64 + cq;
    #pragma unroll
    for (int j = 0; j < 4; ++j)
        *(short4*)(kbp + j*4) = f4tob4(kk[j]);

    #pragma unroll
    for (int j = 0; j < 4; ++j)
        *(short4*)(&sv[sl*68 + cq + j*4]) = f4tob4(vv[j]);
    __syncthreads();

    const int d  = tid >> 2;                   // 0..63
    const int sg = (tid & 3) * 16;             // 0..48
    union { short s[16]; bf16x8 v8[2]; } out;
    #pragma unroll
    for (int i = 0; i < 16; ++i)
        out.s[i] = sv[(sg + i)*68 + d];
    short* vtp = Vtb + ((size_t)g*64 + d)*S_ + s0 + sg;
    *(bf16x8*)(vtp)     = out.v8[0];
    *(bf16x8*)(vtp + 8) = out.v8[1];
}

// ---------------------------------------------------------------------------
// L3 fused mega-kernel, 128-thread blocks.
//   blocks [0, NATT):        attention. Block = (head-pair hp, g, pair p);
//                            wave = one head; q-tiles p and 63-p (17 bodies
//                            each => perfect balance); bf16 LDS staging,
//                            double-buffered, one barrier/tile; P in regs.
//   blocks [NATT, +NCACHE):  cache fill via inverse map (memory-bound,
//                            backfills CU slack while attn runs).
// ---------------------------------------------------------------------------
__global__ __launch_bounds__(128, 2) void fused_kernel(
    const float* __restrict__ q, const short* __restrict__ Kb,
    const short* __restrict__ Vtb, float* __restrict__ o,
    const float4* __restrict__ kin, const float4* __restrict__ vin,
    const float4* __restrict__ kcin, const float4* __restrict__ vcin,
    const int* __restrict__ inv,
    float4* __restrict__ kc, float4* __restrict__ vc)
{
    const int tid = threadIdx.x;
    const int bid = blockIdx.x;

    if (bid >= NATT){
        // ---------------- cache fill ----------------
        int i = (bid - NATT)*128 + tid;        // over SLOTS_*64
        int row = i >> 6;                      // one wave per row: uniform inv
        int n = inv[row];
        if (n >= 0){
            int c = i & 63;
            kc[i] = kin[(size_t)n*64 + c];
            vc[i] = vin[(size_t)n*64 + c];
        } else {
            kc[i] = kcin[i];
            vc[i] = vcin[i];
        }
        return;
    }

    // ---------------- attention ----------------
    __shared__ __align__(16) short sK[2][64*64];   // [buf][key][dim]
    __shared__ __align__(16) short sV[2][64*64];   // [buf][dim][key]

    const int wave = tid >> 6;
    const int lane = tid & 63;
    const int quad = lane >> 4;
    const int l16  = lane & 15;

    const int hp = bid & 1;
    const int g  = (bid >> 1) & 15;
    const int p  = bid >> 5;                   // 0..31
    const int qtA = p, qtB = 63 - p;
    const int ntA = (qtA >> 2) + 1;
    const int ntB = (qtB >> 2) + 1;

    const int b = g >> 2, kvh = g & 3;
    const int h = kvh*4 + hp*2 + wave;

    // ---- Q fragments for both q-tiles (per-lane: row=l16, k=ks*32+quad*8+j)
    bf16x8 qfA[2], qfB[2];
    {
        const float* qpA = q + ((size_t)(b*S_ + qtA*16 + l16))*HD_ + h*D_ + quad*8;
        const float* qpB = q + ((size_t)(b*S_ + qtB*16 + l16))*HD_ + h*D_ + quad*8;
        #pragma unroll
        for (int ks = 0; ks < 2; ++ks){
            float4 a0 = *(const float4*)(qpA + ks*32);
            float4 a1 = *(const float4*)(qpA + ks*32 + 4);
            float4 b0 = *(const float4*)(qpB + ks*32);
            float4 b1 = *(const float4*)(qpB + ks*32 + 4);
            a0.x*=SCL; a0.y*=SCL; a0.z*=SCL; a0.w*=SCL;
            a1.x*=SCL; a1.y*=SCL; a1.z*=SCL; a1.w*=SCL;
            b0.x*=SCL; b0.y*=SCL; b0.z*=SCL; b0.w*=SCL;
            b1.x*=SCL; b1.y*=SCL; b1.z*=SCL; b1.w*=SCL;
            union { short4 s[2]; bf16x8 v8; } ua, ub;
            ua.s[0] = f4tob4(a0); ua.s[1] = f4tob4(a1);
            ub.s[0] = f4tob4(b0); ub.s[1] = f4tob4(b1);
            qfA[ks] = ua.v8; qfB[ks] = ub.v8;
        }
    }

    f32x4 ofA[4], ofB[4];
    #pragma unroll
    for (int f2 = 0; f2 < 4; ++f2){
        ofA[f2] = (f32x4){0.f,0.f,0.f,0.f};
        ofB[f2] = (f32x4){0.f,0.f,0.f,0.f};
    }
    float lsA = 0.f, lsB = 0.f;
    const int qrowA = qtA*16 + l16, qrowB = qtB*16 + l16;

    const short* Kg = Kb  + (size_t)g*S_*64;
    const short* Vg = Vtb + (size_t)g*64*S_;

    // ---- staging: thread owns row rs, 32-col half (4 x bf16x8 per array)
    const int rs = tid >> 1;                   // 0..63
    const int ch = (tid & 1) * 32;             // 0 or 32

    bf16x8 kst[4], vst[4];
    #pragma unroll
    for (int j = 0; j < 4; ++j){
        kst[j] = *(const bf16x8*)(Kg + (size_t)rs*64 + ch + j*8);
        vst[j] = *(const bf16x8*)(Vg + (size_t)rs*S_ + ch + j*8);
    }

    for (int t = 0; t < ntB; ++t){
        short* K_ = (short*)sK[t & 1];
        short* V_ = (short*)sV[t & 1];
        #pragma unroll
        for (int j = 0; j < 4; ++j){
            *(bf16x8*)(&K_[swz(rs, ch + j*8)]) = kst[j];
            *(bf16x8*)(&V_[swz(rs, ch + j*8)]) = vst[j];
        }
        if (t + 1 < ntB){
            #pragma unroll
            for (int j = 0; j < 4; ++j){
                kst[j] = *(const bf16x8*)(Kg + (size_t)((t+1)*64 + rs)*64 + ch + j*8);
                vst[j] = *(const bf16x8*)(Vg + (size_t)rs*S_ + (t+1)*64 + ch + j*8);
            }
        }
        __syncthreads();

        const bool actA = (t < ntA);

        // ---- K-frags once; QK MFMAs for BOTH q-tiles issued before softmax
        bf16x8 kf[2][4];
        #pragma unroll
        for (int ks = 0; ks < 2; ++ks)
            #pragma unroll
            for (int f = 0; f < 4; ++f)
                kf[ks][f] = *(const bf16x8*)(&K_[swz(f*16 + l16, ks*32 + quad*8)]);

        f32x4 scB[4], scA[4];
        #pragma unroll
        for (int f = 0; f < 4; ++f){
            scB[f] = (f32x4){0.f,0.f,0.f,0.f};
            scA[f] = (f32x4){0.f,0.f,0.f,0.f};
        }
        #pragma unroll
        for (int ks = 0; ks < 2; ++ks)
            #pragma unroll
            for (int f = 0; f < 4; ++f)
                scB[f] = __builtin_amdgcn_mfma_f32_16x16x32_bf16(kf[ks][f], qfB[ks], scB[f], 0, 0, 0);
        if (actA){
            #pragma unroll
            for (int ks = 0; ks < 2; ++ks)
                #pragma unroll
                for (int f = 0; f < 4; ++f)
                    scA[f] = __builtin_amdgcn_mfma_f32_16x16x32_bf16(kf[ks][f], qfA[ks], scA[f], 0, 0, 0);
        }

        // ---- softmax for both (VALU overlaps in-flight MFMAs)
        bf16x4 pfB[4], pfA[4];
        #pragma unroll
        for (int f = 0; f < 4; ++f){
            float4 pf;
            #pragma unroll
            for (int r = 0; r < 4; ++r){
                float pe = __builtin_amdgcn_exp2f(scB[f][r]);
                if (t == ntB - 1 && (t*64 + f*16 + quad*4 + r > qrowB)) pe = 0.f;
                lsB += pe;
                ((float*)&pf)[r] = pe;
            }
            union { short4 s; bf16x4 bv; } u; u.s = f4tob4(pf);
            pfB[f] = u.bv;
        }
        if (actA){
            #pragma unroll
            for (int f = 0; f < 4; ++f){
                float4 pf;
                #pragma unroll
                for (int r = 0; r < 4; ++r){
                    float pe = __builtin_amdgcn_exp2f(scA[f][r]);
                    if (t == ntA - 1 && (t*64 + f*16 + quad*4 + r > qrowA)) pe = 0.f;
                    lsA += pe;
                    ((float*)&pf)[r] = pe;
                }
                union { short4 s; bf16x4 bv; } u; u.s = f4tob4(pf);
                pfA[f] = u.bv;
            }
        }

        // ---- PV: each V-frag loaded once, used by both q-tiles
        #pragma unroll
        for (int f = 0; f < 4; ++f){
            #pragma unroll
            for (int f2 = 0; f2 < 4; ++f2){
                bf16x4 vf = *(const bf16x4*)(&V_[swz(f2*16 + l16, f*16 + quad*4)]);
                ofB[f2] = __builtin_amdgcn_mfma_f32_16x16x16bf16_1k(pfB[f], vf, ofB[f2], 0, 0, 0);
                if (actA)
                    ofA[f2] = __builtin_amdgcn_mfma_f32_16x16x16bf16_1k(pfA[f], vf, ofA[f2], 0, 0, 0);
            }
        }
    }

    // ---- epilogues
    auto epilogue = [&](f32x4* of, float lsum, int qt){
        lsum += __shfl_xor(lsum, 16);
        lsum += __shfl_xor(lsum, 32);
        float linv[4];
        #pragma unroll
        for (int r = 0; r < 4; ++r)
            linv[r] = 1.f / __shfl(lsum, quad*4 + r);
        #pragma unroll
        for (int f2 = 0; f2 < 4; ++f2){
            #pragma unroll
            for (int r = 0; r < 4; ++r){
                const int row = qt*16 + quad*4 + r;
                o[((size_t)(b*S_ + row))*HD_ + h*D_ + f2*16 + l16] = of[f2][r] * linv[r];
            }
        }
    };
    epilogue(ofA, lsA, qtA);
    epilogue(ofB, lsB, qtB);
}

// ---------------------------------------------------------------------------
extern "C" void kernel_launch(void* const* d_in, const int* in_sizes, int n_in,
                              void* d_out, int out_size, void* d_ws, size_t ws_size,
                              hipStream_t stream){
    (void)in_sizes; (void)n_in; (void)out_size; (void)ws_size;
    const float* q     = (const float*)d_in[0];
    const float* k     = (const float*)d_in[1];
    const float* v     = (const float*)d_in[2];
    const float* kc_in = (const float*)d_in[3];
    const float* vc_in = (const float*)d_in[4];
    const int*   slot  = (const int*)d_in[5];

    float* o  = (float*)d_out;
    float* kc = o + (size_t)N_*HD_;
    float* vc = kc + (size_t)SLOTS_*KVD_;

    short* Kb  = (short*)d_ws;                             // 2 MB
    short* Vt  = Kb + (size_t)16*S_*64;                    // 2 MB
    int*   inv = (int*)((char*)d_ws + (4u << 20));         // 32 KB

    inv_init<<<SLOTS_/256, 256, 0, stream>>>(inv);

    prep_kernel<<<256 + N_/256, 256, 0, stream>>>(k, v, slot, inv, Kb, Vt);

    fused_kernel<<<NATT + NCACHE, 128, 0, stream>>>(
        q, Kb, Vt, o,
        (const float4*)k, (const float4*)v,
        (const float4*)kc_in, (const float4*)vc_in, inv,
        (float4*)kc, (float4*)vc);
}